// Round 22
// baseline (44.511 us; speedup 1.0000x reference)
//
#include <hip/hip_runtime.h>
#include <hip/hip_bf16.h>

// LogicConv3d: B=64, C=32, H=32, W=32, K=64, P=784, S=16 gathers/side.
// R22: clean 2-blocks/CU occupancy test (the one configuration never tried).
//  - R18 (best, 28.7): 1 block/CU forced by 128KB LDS tile -> 4 waves/SIMD.
//  - Every prior occupancy attempt had a confound: forced launch_bounds
//    (R13/R15/R19 -> 32 VGPR spills), split output rows (R19 write-amp),
//    doubled L2 volume (R21).
//  - R22: stage only channels 0..15 of even image (64KB contiguous) ->
//    2 blocks/CU = 8 waves/SIMD. Even-role waves: c<16 leaves from LDS,
//    c>=16 from L2 (base<65536 test is s_load scalar -> uniform branch).
//    Odd-role waves: unchanged quad L2 gathers. Full output rows, no
//    forced bounds, R18's natural-64-VGPR loop bodies.
//  - Grid 512 = bp_hi(8,slow) x kq(16) x bp_lo(4,fast): ~1.5MB concurrent
//    set per XCD L2; each image pair read by 2 XCDs (12MB L3 total).
//  - 4 k's per block; 2 waves per (role,k) split the p-range (sub=0/1).

#define B_  64
#define C_  32
#define H_  32
#define W_  32
#define K_  64
#define P_  784
#define CHW (C_*H_*W_)      // 32768 floats = 128 KB
#define HW  (H_*W_)         // 1024
#define SITES (K_*P_)       // 50176
#define NPAIR (P_/2)        // 392
#define NQUAD (P_/4)        // 196

__constant__ float COEF_[16][4] = {
    {0, 0, 0, 0}, {0, 0, 0, 1}, {0, 1, 0, -1}, {0, 1, 0, 0},
    {0, 0, 1, -1}, {0, 0, 1, 0}, {0, 1, 1, -2}, {0, 1, 1, -1},
    {1, -1, -1, 1}, {1, -1, -1, 2}, {1, 0, -1, 0}, {1, 0, -1, 1},
    {1, -1, 0, 0}, {1, -1, 0, 1}, {1, 0, 0, -1}, {1, 0, 0, 0}
};

typedef float f2u __attribute__((ext_vector_type(2), aligned(4)));
typedef float f4a __attribute__((ext_vector_type(4), aligned(4)));

// ---- kernel 1: tiny prep = bases (0..2047) + coefs (2048..4031) ----
__global__ __launch_bounds__(256) void prep_kernel(
    const int* __restrict__ a_idx, const int* __restrict__ b_idx,
    const float* __restrict__ w0, const float* __restrict__ w1,
    const float* __restrict__ w2, const float* __restrict__ w3,
    const float* __restrict__ w4,
    int* __restrict__ baseAB,        // [K_][32] byte offsets
    float4* __restrict__ cws)        // [K_*31]
{
    const int t = blockIdx.x * 256 + threadIdx.x;
    if (t < K_ * 32) {
        const int k = t >> 5;
        const int j = t & 31;
        const int* src = (j < 16) ? a_idx : b_idx;
        const int l = j & 15;
        const size_t ii = ((size_t)k * P_ * 16 + l) * 3;   // site (k, p=0, l)
        const int h = src[ii + 0];
        const int w = src[ii + 1];
        const int c = src[ii + 2];
        baseAB[t] = (c << 12) + (h << 7) + (w << 2);       // bytes
    } else if (t < K_ * 32 + K_ * 31) {
        const int tt = t - K_ * 32;
        const int k = tt / 31;
        const int node = tt - k * 31;
        int d, l;
        if      (node < 16) { d = 0; l = node; }
        else if (node < 24) { d = 1; l = node - 16; }
        else if (node < 28) { d = 2; l = node - 24; }
        else if (node < 30) { d = 3; l = node - 28; }
        else                { d = 4; l = 0; }
        const float* W;
        switch (d) {
            case 0: W = w0; break;
            case 1: W = w1; break;
            case 2: W = w2; break;
            case 3: W = w3; break;
            default: W = w4; break;
        }
        const float* row = W + ((size_t)l * K_ + k) * 16;
        float m = row[0];
        #pragma unroll
        for (int o = 1; o < 16; ++o) m = fmaxf(m, row[o]);
        float e[16];
        float Z = 0.0f;
        #pragma unroll
        for (int o = 0; o < 16; ++o) { e[o] = expf(row[o] - m); Z += e[o]; }
        const float inv = 1.0f / Z;
        float c0 = 0.f, c1 = 0.f, c2 = 0.f, c3 = 0.f;
        #pragma unroll
        for (int o = 0; o < 16; ++o) {
            c0 += e[o] * COEF_[o][0];
            c1 += e[o] * COEF_[o][1];
            c2 += e[o] * COEF_[o][2];
            c3 += e[o] * COEF_[o][3];
        }
        cws[tt] = make_float4(c0 * inv, c1 * inv, c2 * inv, c3 * inv);
    }
}

// y = c0 + c1*a + c2*b + c3*a*b == fma(b, fma(c3,a,c2), fma(c1,a,c0))
__device__ __forceinline__ float binop(float a, float b, float4 c) {
    return fmaf(b, fmaf(c.w, a, c.z), fmaf(c.y, a, c.x));
}

// ---- kernel 2: main. 1024 thr, 64 KB LDS -> 2 blocks/CU. ----
__global__ __launch_bounds__(1024) void logicconv_main(
    const float* __restrict__ x,
    const int* __restrict__ baseAB,
    const float4* __restrict__ cws,
    float* __restrict__ out)
{
    __shared__ float simg[16384];   // 64 KB: channels 0..15 of even image

    const int tid   = threadIdx.x;
    const int bid   = blockIdx.x;
    const int bp_hi = bid >> 6;          // 0..7  (slow)
    const int mid   = bid & 63;
    const int kq    = mid >> 2;          // 0..15
    const int bp_lo = mid & 3;           // 0..3  (fast)
    const int bp    = bp_hi * 4 + bp_lo; // 0..31
    const int b0    = bp * 2;

    // ---- stage channels 0..15 of even image (contiguous 64 KB) ----
    {
        const float4* xi = (const float4*)(x + (size_t)b0 * CHW);
        float4* si = (float4*)simg;
        #pragma unroll
        for (int j = 0; j < 4; ++j)
            si[tid + j * 1024] = xi[tid + j * 1024];
    }
    __syncthreads();

    // ---- 16 waves: role x sub x klocal ----
    const int w      = __builtin_amdgcn_readfirstlane(tid >> 6);   // 0..15
    const int lane   = tid & 63;
    const int isOdd  = (w >> 2) & 1;                // image parity (mixes across SIMDs)
    const int r3     = (w & 3) | ((w >> 3) << 2);   // 0..7
    const int klocal = r3 >> 1;                     // 0..3
    const int sub    = r3 & 1;                      // p-range half
    const int k      = kq * 4 + klocal;

    const int*    __restrict__ bA = baseAB + k * 32;          // s_load
    const float4* __restrict__ cw = cws + (size_t)k * 31;     // s_load

    if (!isOdd) {
        // ======== EVEN image: pair gathers, LDS (c<16) / global (c>=16) ========
        const char* sb = (const char*)simg;
        const char* xe = (const char*)(x + (size_t)b0 * CHW);
        float* __restrict__ o0 = out + ((size_t)b0 * K_ + k) * P_;
        for (int s = 0; s < 4; ++s) {
            const int tl = s * 64 + lane;          // local pair index
            if (tl < 196) {
                const int t = sub * 196 + tl;      // global pair index
                const unsigned row  = (unsigned)t / 14u;
                const unsigned disp = 8u * (unsigned)t + 16u * row;

                float2 y1[8];
                #pragma unroll
                for (int q = 0; q < 2; ++q) {      // halves of 8 leaves
                    float ev[32];
                    #pragma unroll
                    for (int j = 0; j < 8; ++j) {
                        const int l = q * 8 + j;
                        const int baA = bA[l];
                        const int baB = bA[16 + l];
                        if (baA < 65536) {         // uniform (scalar) branch
                            const unsigned la = (unsigned)baA + disp;
                            ev[4*j+0] = *(const float*)(sb + la);
                            ev[4*j+1] = *(const float*)(sb + la + 4);
                        } else {
                            const f2u va = *(const f2u*)(xe + ((unsigned)baA + disp));
                            ev[4*j+0] = va.x;
                            ev[4*j+1] = va.y;
                        }
                        if (baB < 65536) {
                            const unsigned lb = (unsigned)baB + disp;
                            ev[4*j+2] = *(const float*)(sb + lb);
                            ev[4*j+3] = *(const float*)(sb + lb + 4);
                        } else {
                            const f2u vb = *(const f2u*)(xe + ((unsigned)baB + disp));
                            ev[4*j+2] = vb.x;
                            ev[4*j+3] = vb.y;
                        }
                    }
                    #pragma unroll
                    for (int j = 0; j < 4; ++j) {  // layer0 + layer1 folded
                        const int l0 = q * 8 + 2 * j;
                        const int n  = q * 4 + j;
                        const float4 cA = cw[l0], cB = cw[l0 + 1];
                        const float4 cL = cw[16 + n];
                        const float z0x = binop(ev[8*j+0], ev[8*j+2], cA);
                        const float z0y = binop(ev[8*j+1], ev[8*j+3], cA);
                        const float z1x = binop(ev[8*j+4], ev[8*j+6], cB);
                        const float z1y = binop(ev[8*j+5], ev[8*j+7], cB);
                        y1[n].x = binop(z0x, z1x, cL);
                        y1[n].y = binop(z0y, z1y, cL);
                    }
                }
                float2 y2[4];
                #pragma unroll
                for (int l = 0; l < 4; ++l) {
                    const float4 c = cw[24 + l];
                    y2[l].x = binop(y1[2*l].x, y1[2*l+1].x, c);
                    y2[l].y = binop(y1[2*l].y, y1[2*l+1].y, c);
                }
                float2 y3[2];
                #pragma unroll
                for (int l = 0; l < 2; ++l) {
                    const float4 c = cw[28 + l];
                    y3[l].x = binop(y2[2*l].x, y2[2*l+1].x, c);
                    y3[l].y = binop(y2[2*l].y, y2[2*l+1].y, c);
                }
                const float4 c4 = cw[30];
                float2 re;
                re.x = binop(y3[0].x, y3[1].x, c4);
                re.y = binop(y3[0].y, y3[1].y, c4);
                *(float2*)(o0 + 2 * t) = re;       // 8B aligned
            }
        }
    } else {
        // ======== ODD image: global quad-gathers (vmem pipe) ========
        const char* x1 = (const char*)(x + (size_t)(b0 + 1) * CHW);
        float* __restrict__ o1 = out + ((size_t)(b0 + 1) * K_ + k) * P_;
        for (int s = 0; s < 2; ++s) {
            const int tl = s * 64 + lane;          // local quad index
            if (tl < 98) {
                const int t = sub * 98 + tl;       // global quad index
                const unsigned row  = (unsigned)t / 7u;     // (4t)/28
                const unsigned disp = 16u * (unsigned)t + 16u * row;

                f4a y1[8];
                #pragma unroll
                for (int q = 0; q < 4; ++q) {      // 4 leaves per chunk
                    f4a v[8];
                    #pragma unroll
                    for (int j = 0; j < 4; ++j) {
                        const int l = q * 4 + j;
                        v[2*j]   = *(const f4a*)(x1 + ((unsigned)bA[l]      + disp));
                        v[2*j+1] = *(const f4a*)(x1 + ((unsigned)bA[16 + l] + disp));
                    }
                    #pragma unroll
                    for (int j = 0; j < 2; ++j) {  // layer0 + layer1 folded
                        const int l0 = q * 4 + 2 * j;
                        const int n  = q * 2 + j;
                        const float4 cA = cw[l0], cB = cw[l0 + 1];
                        const float4 cL = cw[16 + n];
                        f4a z0, z1;
                        #pragma unroll
                        for (int e = 0; e < 4; ++e) {
                            z0[e] = binop(v[4*j    ][e], v[4*j + 1][e], cA);
                            z1[e] = binop(v[4*j + 2][e], v[4*j + 3][e], cB);
                        }
                        #pragma unroll
                        for (int e = 0; e < 4; ++e)
                            y1[n][e] = binop(z0[e], z1[e], cL);
                    }
                }
                f4a y2[4];
                #pragma unroll
                for (int l = 0; l < 4; ++l) {
                    const float4 c = cw[24 + l];
                    #pragma unroll
                    for (int e = 0; e < 4; ++e)
                        y2[l][e] = binop(y1[2*l][e], y1[2*l+1][e], c);
                }
                f4a y3[2];
                #pragma unroll
                for (int l = 0; l < 2; ++l) {
                    const float4 c = cw[28 + l];
                    #pragma unroll
                    for (int e = 0; e < 4; ++e)
                        y3[l][e] = binop(y2[2*l][e], y2[2*l+1][e], c);
                }
                const float4 c4 = cw[30];
                float4 ro;
                ro.x = binop(y3[0][0], y3[1][0], c4);
                ro.y = binop(y3[0][1], y3[1][1], c4);
                ro.z = binop(y3[0][2], y3[1][2], c4);
                ro.w = binop(y3[0][3], y3[1][3], c4);
                *(float4*)(o1 + 4 * t) = ro;       // 16B aligned
            }
        }
    }
}

extern "C" void kernel_launch(void* const* d_in, const int* in_sizes, int n_in,
                              void* d_out, int out_size, void* d_ws, size_t ws_size,
                              hipStream_t stream) {
    const float* x     = (const float*)d_in[0];
    const float* w0    = (const float*)d_in[1];
    const float* w1    = (const float*)d_in[2];
    const float* w2    = (const float*)d_in[3];
    const float* w3    = (const float*)d_in[4];
    const float* w4    = (const float*)d_in[5];
    const int*   a_idx = (const int*)d_in[6];
    const int*   b_idx = (const int*)d_in[7];
    float* out = (float*)d_out;

    // ws layout: baseAB (8 KB) | cws (32 KB)
    int*    baseAB = (int*)d_ws;
    float4* cws    = (float4*)((char*)d_ws + (size_t)K_ * 32 * 4);

    prep_kernel<<<16, 256, 0, stream>>>(a_idx, b_idx, w0, w1, w2, w3, w4,
                                        baseAB, cws);

    logicconv_main<<<512, 1024, 0, stream>>>(x, baseAB, cws, out);
}

// Round 23
// 28.328 us; speedup vs baseline: 1.5712x; 1.5712x over previous
//
#include <hip/hip_runtime.h>
#include <hip/hip_bf16.h>

// LogicConv3d: B=64, C=32, H=32, W=32, K=64, P=784, S=16 gathers/side.
// R23 = R18 restored (best measured: 28.7us across 22 structural variants).
//  - Role-split waves: 8 waves gather the even image from LDS (ds pipe,
//    pair granularity); 8 waves gather the odd image from L2 (vmem pipe,
//    quad dwordx4). img=(w>>2)&1 mixes roles across SIMDs so both pipes
//    issue concurrently on every SIMD.
//  - Mandatory gather traffic (~411MB of 4B granules) split ~50/50 across
//    the two pipes; VALU tree fills stalls.
//  - Occupancy fixed at 1 block/CU (128KB LDS): proven optimal — all 2x
//    occupancy attempts (R13/R15/R19/R21/R22, incl. the confound-free R22)
//    regressed.
//  - 2-kernel skeleton: tiny prep packs analytic bases (offset = base(k,l)
//    + disp(p)) and softmax-COEF tables; main reads them via s_load.

#define B_  64
#define C_  32
#define H_  32
#define W_  32
#define K_  64
#define P_  784
#define CHW (C_*H_*W_)      // 32768 floats = 128 KB
#define HW  (H_*W_)         // 1024
#define SITES (K_*P_)       // 50176
#define NPAIR (P_/2)        // 392
#define NQUAD (P_/4)        // 196

__constant__ float COEF_[16][4] = {
    {0, 0, 0, 0}, {0, 0, 0, 1}, {0, 1, 0, -1}, {0, 1, 0, 0},
    {0, 0, 1, -1}, {0, 0, 1, 0}, {0, 1, 1, -2}, {0, 1, 1, -1},
    {1, -1, -1, 1}, {1, -1, -1, 2}, {1, 0, -1, 0}, {1, 0, -1, 1},
    {1, -1, 0, 0}, {1, -1, 0, 1}, {1, 0, 0, -1}, {1, 0, 0, 0}
};

typedef float f4a __attribute__((ext_vector_type(4), aligned(4)));

// ---- kernel 1: tiny prep = bases (0..2047) + coefs (2048..4031) ----
__global__ __launch_bounds__(256) void prep_kernel(
    const int* __restrict__ a_idx, const int* __restrict__ b_idx,
    const float* __restrict__ w0, const float* __restrict__ w1,
    const float* __restrict__ w2, const float* __restrict__ w3,
    const float* __restrict__ w4,
    int* __restrict__ baseAB,        // [K_][32] byte offsets
    float4* __restrict__ cws)        // [K_*31]
{
    const int t = blockIdx.x * 256 + threadIdx.x;
    if (t < K_ * 32) {
        const int k = t >> 5;
        const int j = t & 31;
        const int* src = (j < 16) ? a_idx : b_idx;
        const int l = j & 15;
        const size_t ii = ((size_t)k * P_ * 16 + l) * 3;   // site (k, p=0, l)
        const int h = src[ii + 0];
        const int w = src[ii + 1];
        const int c = src[ii + 2];
        baseAB[t] = (c << 12) + (h << 7) + (w << 2);       // bytes
    } else if (t < K_ * 32 + K_ * 31) {
        const int tt = t - K_ * 32;
        const int k = tt / 31;
        const int node = tt - k * 31;
        int d, l;
        if      (node < 16) { d = 0; l = node; }
        else if (node < 24) { d = 1; l = node - 16; }
        else if (node < 28) { d = 2; l = node - 24; }
        else if (node < 30) { d = 3; l = node - 28; }
        else                { d = 4; l = 0; }
        const float* W;
        switch (d) {
            case 0: W = w0; break;
            case 1: W = w1; break;
            case 2: W = w2; break;
            case 3: W = w3; break;
            default: W = w4; break;
        }
        const float* row = W + ((size_t)l * K_ + k) * 16;
        float m = row[0];
        #pragma unroll
        for (int o = 1; o < 16; ++o) m = fmaxf(m, row[o]);
        float e[16];
        float Z = 0.0f;
        #pragma unroll
        for (int o = 0; o < 16; ++o) { e[o] = expf(row[o] - m); Z += e[o]; }
        const float inv = 1.0f / Z;
        float c0 = 0.f, c1 = 0.f, c2 = 0.f, c3 = 0.f;
        #pragma unroll
        for (int o = 0; o < 16; ++o) {
            c0 += e[o] * COEF_[o][0];
            c1 += e[o] * COEF_[o][1];
            c2 += e[o] * COEF_[o][2];
            c3 += e[o] * COEF_[o][3];
        }
        cws[tt] = make_float4(c0 * inv, c1 * inv, c2 * inv, c3 * inv);
    }
}

// y = c0 + c1*a + c2*b + c3*a*b == fma(b, fma(c3,a,c2), fma(c1,a,c0))
__device__ __forceinline__ float binop(float a, float b, float4 c) {
    return fmaf(b, fmaf(c.w, a, c.z), fmaf(c.y, a, c.x));
}

// ---- kernel 2: main. bid = kg*32 + bp. 1024 thr, 1 block/CU. ----
__global__ __launch_bounds__(1024, 4) void logicconv_main(
    const float* __restrict__ x,
    const int* __restrict__ baseAB,
    const float4* __restrict__ cws,
    float* __restrict__ out)
{
    __shared__ float simg[CHW];   // even image, 128 KB

    const int tid = threadIdx.x;
    const int kg  = blockIdx.x >> 5;   // 0..7  (slow)
    const int bp  = blockIdx.x & 31;   // 0..31 (fast)
    const int b0  = bp * 2;

    // ---- stage even image (all 1024 threads, coalesced float4) ----
    {
        const float4* xi = (const float4*)(x + (size_t)b0 * CHW);
        float4* si = (float4*)simg;
        #pragma unroll
        for (int j = 0; j < 8; ++j)
            si[tid + j * 1024] = xi[tid + j * 1024];
    }
    __syncthreads();

    // ---- wave roles: img = bit2 of wave (mixes roles across SIMDs) ----
    const int w    = __builtin_amdgcn_readfirstlane(tid >> 6);   // 0..15
    const int lane = tid & 63;
    const int isOdd = (w >> 2) & 1;                 // image parity
    const int kloc  = (w & 3) | ((w >> 3) << 2);    // 0..7 (bijective w/ isOdd)
    const int k     = kg * 8 + kloc;

    const int*    __restrict__ bA = baseAB + k * 32;          // s_load
    const float4* __restrict__ cw = cws + (size_t)k * 31;     // s_load

    if (!isOdd) {
        // ======== EVEN image: LDS pair-gathers (ds pipe) ========
        const char* sb = (const char*)simg;
        float* __restrict__ o0 = out + ((size_t)b0 * K_ + k) * P_;
        for (int s = 0; s < 7; ++s) {
            const int t = s * 64 + lane;           // pair index
            if (t < NPAIR) {
                const unsigned row  = (unsigned)t / 14u;
                const unsigned disp = 8u * (unsigned)t + 16u * row;

                float2 y1[8];
                #pragma unroll
                for (int q = 0; q < 2; ++q) {      // halves of 8 leaves
                    float ev[32];
                    #pragma unroll
                    for (int j = 0; j < 8; ++j) {
                        const int l = q * 8 + j;
                        const unsigned la = (unsigned)bA[l]      + disp;
                        const unsigned lb = (unsigned)bA[16 + l] + disp;
                        ev[4*j+0] = *(const float*)(sb + la);
                        ev[4*j+1] = *(const float*)(sb + la + 4);
                        ev[4*j+2] = *(const float*)(sb + lb);
                        ev[4*j+3] = *(const float*)(sb + lb + 4);
                    }
                    #pragma unroll
                    for (int j = 0; j < 4; ++j) {  // layer0 + layer1 folded
                        const int l0 = q * 8 + 2 * j;
                        const int n  = q * 4 + j;
                        const float4 cA = cw[l0], cB = cw[l0 + 1];
                        const float4 cL = cw[16 + n];
                        const float z0x = binop(ev[8*j+0], ev[8*j+2], cA);
                        const float z0y = binop(ev[8*j+1], ev[8*j+3], cA);
                        const float z1x = binop(ev[8*j+4], ev[8*j+6], cB);
                        const float z1y = binop(ev[8*j+5], ev[8*j+7], cB);
                        y1[n].x = binop(z0x, z1x, cL);
                        y1[n].y = binop(z0y, z1y, cL);
                    }
                }
                float2 y2[4];
                #pragma unroll
                for (int l = 0; l < 4; ++l) {
                    const float4 c = cw[24 + l];
                    y2[l].x = binop(y1[2*l].x, y1[2*l+1].x, c);
                    y2[l].y = binop(y1[2*l].y, y1[2*l+1].y, c);
                }
                float2 y3[2];
                #pragma unroll
                for (int l = 0; l < 2; ++l) {
                    const float4 c = cw[28 + l];
                    y3[l].x = binop(y2[2*l].x, y2[2*l+1].x, c);
                    y3[l].y = binop(y2[2*l].y, y2[2*l+1].y, c);
                }
                const float4 c4 = cw[30];
                float2 re;
                re.x = binop(y3[0].x, y3[1].x, c4);
                re.y = binop(y3[0].y, y3[1].y, c4);
                *(float2*)(o0 + 2 * t) = re;
            }
        }
    } else {
        // ======== ODD image: global quad-gathers (vmem pipe) ========
        const char* x1 = (const char*)(x + (size_t)(b0 + 1) * CHW);
        float* __restrict__ o1 = out + ((size_t)(b0 + 1) * K_ + k) * P_;
        for (int s = 0; s < 4; ++s) {
            const int t = s * 64 + lane;           // quad index
            if (t < NQUAD) {
                const unsigned row  = (unsigned)t / 7u;     // (4t)/28
                const unsigned disp = 16u * (unsigned)t + 16u * row;

                f4a y1[8];
                #pragma unroll
                for (int q = 0; q < 4; ++q) {      // 4 leaves per chunk
                    f4a v[8];
                    #pragma unroll
                    for (int j = 0; j < 4; ++j) {
                        const int l = q * 4 + j;
                        v[2*j]   = *(const f4a*)(x1 + ((unsigned)bA[l]      + disp));
                        v[2*j+1] = *(const f4a*)(x1 + ((unsigned)bA[16 + l] + disp));
                    }
                    #pragma unroll
                    for (int j = 0; j < 2; ++j) {  // layer0 + layer1 folded
                        const int l0 = q * 4 + 2 * j;
                        const int n  = q * 2 + j;
                        const float4 cA = cw[l0], cB = cw[l0 + 1];
                        const float4 cL = cw[16 + n];
                        f4a z0, z1;
                        #pragma unroll
                        for (int e = 0; e < 4; ++e) {
                            z0[e] = binop(v[4*j    ][e], v[4*j + 1][e], cA);
                            z1[e] = binop(v[4*j + 2][e], v[4*j + 3][e], cB);
                        }
                        #pragma unroll
                        for (int e = 0; e < 4; ++e)
                            y1[n][e] = binop(z0[e], z1[e], cL);
                    }
                }
                f4a y2[4];
                #pragma unroll
                for (int l = 0; l < 4; ++l) {
                    const float4 c = cw[24 + l];
                    #pragma unroll
                    for (int e = 0; e < 4; ++e)
                        y2[l][e] = binop(y1[2*l][e], y1[2*l+1][e], c);
                }
                f4a y3[2];
                #pragma unroll
                for (int l = 0; l < 2; ++l) {
                    const float4 c = cw[28 + l];
                    #pragma unroll
                    for (int e = 0; e < 4; ++e)
                        y3[l][e] = binop(y2[2*l][e], y2[2*l+1][e], c);
                }
                const float4 c4 = cw[30];
                float4 ro;
                ro.x = binop(y3[0][0], y3[1][0], c4);
                ro.y = binop(y3[0][1], y3[1][1], c4);
                ro.z = binop(y3[0][2], y3[1][2], c4);
                ro.w = binop(y3[0][3], y3[1][3], c4);
                *(float4*)(o1 + 4 * t) = ro;       // 16B aligned
            }
        }
    }
}

extern "C" void kernel_launch(void* const* d_in, const int* in_sizes, int n_in,
                              void* d_out, int out_size, void* d_ws, size_t ws_size,
                              hipStream_t stream) {
    const float* x     = (const float*)d_in[0];
    const float* w0    = (const float*)d_in[1];
    const float* w1    = (const float*)d_in[2];
    const float* w2    = (const float*)d_in[3];
    const float* w3    = (const float*)d_in[4];
    const float* w4    = (const float*)d_in[5];
    const int*   a_idx = (const int*)d_in[6];
    const int*   b_idx = (const int*)d_in[7];
    float* out = (float*)d_out;

    // ws layout: baseAB (8 KB) | cws (32 KB)
    int*    baseAB = (int*)d_ws;
    float4* cws    = (float4*)((char*)d_ws + (size_t)K_ * 32 * 4);

    prep_kernel<<<16, 256, 0, stream>>>(a_idx, b_idx, w0, w1, w2, w3, w4,
                                        baseAB, cws);

    logicconv_main<<<256, 1024, 0, stream>>>(x, baseAB, cws, out);
}